// Round 5
// baseline (531.988 us; speedup 1.0000x reference)
//
#include <hip/hip_runtime.h>

#define S_LEN 2048
#define HDIM  2048
#define NHEADS 16
#define DHEAD 128
#define BATCH 2
#define MROWS (BATCH * S_LEN)   // 4096
#define QKVN  (3 * HDIM)        // 6144

typedef _Float16 f16;
typedef _Float16 f16x8 __attribute__((ext_vector_type(8)));
typedef _Float16 f16x4 __attribute__((ext_vector_type(4)));
typedef float    f32x4 __attribute__((ext_vector_type(4)));
typedef float    f32x16 __attribute__((ext_vector_type(16)));

typedef const __attribute__((address_space(1))) void* gas_ptr;
typedef __attribute__((address_space(3))) void*       las_ptr;

#define MFMA16(a, b, c)  __builtin_amdgcn_mfma_f32_16x16x32_f16(a, b, c, 0, 0, 0)
#define MFMA32(a, b, c)  __builtin_amdgcn_mfma_f32_32x32x16_f16(a, b, c, 0, 0, 0)

__device__ __forceinline__ void gl_lds16(const f16* g, f16* lds_wave_base) {
  __builtin_amdgcn_global_load_lds((gas_ptr)g, (las_ptr)lds_wave_base, 16, 0, 0);
}

// Blocked tile layout for GEMM operands: tile (rt, kt) of logical [rows][K] f16,
// 128 rows x 32 k, stored as [kc(4)][r(128)][8] (8 KB) at tile index rt*(K/32)+kt.

// ---------------- fused prep: X cvt + both weight transposes ------------------
__device__ __forceinline__ void transpose_tile(const float* __restrict__ W,
                                               f16* __restrict__ Wb,
                                               int K, int N, int k0, int n0,
                                               float* tile /*[64][65]*/) {
  int tr = threadIdx.x >> 4;
  int tc = (threadIdx.x & 15) * 4;
  int KT = K >> 5;
#pragma unroll
  for (int rr = 0; rr < 4; ++rr) {
    int r = rr * 16 + tr;
    float4 v = *(const float4*)(W + (size_t)(k0 + r) * N + n0 + tc);
    tile[r * 65 + tc + 0] = v.x; tile[r * 65 + tc + 1] = v.y;
    tile[r * 65 + tc + 2] = v.z; tile[r * 65 + tc + 3] = v.w;
  }
  __syncthreads();
#pragma unroll
  for (int rr = 0; rr < 4; ++rr) {
    int r = rr * 16 + tr;
    int n = n0 + r;
    int kBase = k0 + tc;
    f16x4 o;
#pragma unroll
    for (int c = 0; c < 4; ++c) o[c] = (f16)tile[(tc + c) * 65 + r];
    int nt = n >> 7, nn = n & 127;
    int kt = kBase >> 5, kc = (kBase >> 3) & 3, j = kBase & 7;
    *(f16x4*)(Wb + ((size_t)nt * KT + kt) * 4096 + (kc * 128 + nn) * 8 + j) = o;
  }
}

__global__ __launch_bounds__(256) void prep_kernel(const float* __restrict__ X,
                                                   f16* __restrict__ Xb,
                                                   const float* __restrict__ Wqkv,
                                                   f16* __restrict__ Wqkvb,
                                                   const float* __restrict__ Wout,
                                                   f16* __restrict__ Woutb) {
  __shared__ float tile[64 * 65];
  int bz = blockIdx.x;
  if (bz < 2048) {
    int kt = bz & 63, rt = bz >> 6;
    int t = threadIdx.x;
    int m = t >> 1, half = t & 1;
    const float* src = X + (size_t)(rt * 128 + m) * HDIM + kt * 32 + half * 16;
    float4 v0 = ((const float4*)src)[0];
    float4 v1 = ((const float4*)src)[1];
    float4 v2 = ((const float4*)src)[2];
    float4 v3 = ((const float4*)src)[3];
    f16x8 a = {(f16)v0.x, (f16)v0.y, (f16)v0.z, (f16)v0.w,
               (f16)v1.x, (f16)v1.y, (f16)v1.z, (f16)v1.w};
    f16x8 b = {(f16)v2.x, (f16)v2.y, (f16)v2.z, (f16)v2.w,
               (f16)v3.x, (f16)v3.y, (f16)v3.z, (f16)v3.w};
    f16* dst = Xb + ((size_t)rt * 64 + kt) * 4096 + ((half * 2) * 128 + m) * 8;
    *(f16x8*)dst = a;
    *(f16x8*)(dst + 1024) = b;
  } else if (bz < 5120) {
    int u = bz - 2048;                 // 96 n-blocks x 32 k-blocks
    int nx = u % 96, ky = u / 96;
    transpose_tile(Wqkv, Wqkvb, HDIM, QKVN, ky * 64, nx * 64, tile);
  } else {
    int u = bz - 5120;                 // 32 x 32
    int nx = u & 31, ky = u >> 5;
    transpose_tile(Wout, Woutb, HDIM, HDIM, ky * 64, nx * 64, tile);
  }
}

// ---------------- QKV GEMM: 256x384 tile, 8-wave, 3-buffer pipeline ----------
// EXACT R3 form (measured 114us): phase-locked cadence reads->barrier->
// lgkmcnt(0)->setprio 16-MFMA clusters; R4's rebalance/drain-removal regressed
// (137us) -- do not touch this schedule.
__global__ __launch_bounds__(512, 2) void gemm_qkv_kernel(const f16* __restrict__ Ablk,
                                                          const f16* __restrict__ Bblk,
                                                          const float* __restrict__ bias,
                                                          f16* __restrict__ Qr,
                                                          f16* __restrict__ KB,
                                                          f16* __restrict__ VB) {
  __shared__ f16 As[3][2][4096];   // [buf][row-half 128][blocked 128x32 tile]
  __shared__ f16 Bs[3][3][4096];   // [buf][col-third 128][blocked 128x32 tile]
  const int tid = threadIdx.x;
  const int lane = tid & 63, wv = tid >> 6;
  const int lhi = lane >> 4, llo = lane & 15;
  const int wr = wv >> 2, wc = wv & 3;       // 2M x 4N wave grid; wave owns 128x96

  // XCD-chunked swizzle: each XCD gets a 4bx x 8by cell (panel L2 locality)
  int lin = blockIdx.x + 16 * blockIdx.y;
  int xcd = lin & 7, slot = lin >> 3;        // slot in [0,32)
  int bx = (xcd & 3) * 4 + (slot & 3);
  int by = (xcd >> 2) * 8 + (slot >> 2);

  const int KT = HDIM >> 5;                  // 64 K-tiles
  const f16* Ab0 = Ablk + (size_t)(2 * by)     * KT * 4096;
  const f16* Ab1 = Ablk + (size_t)(2 * by + 1) * KT * 4096;
  const f16* Bb0 = Bblk + (size_t)(3 * bx)     * KT * 4096;
  const f16* Bb1 = Bblk + (size_t)(3 * bx + 1) * KT * 4096;
  const f16* Bb2 = Bblk + (size_t)(3 * bx + 2) * KT * 4096;

  f32x4 acc[8][6];
#pragma unroll
  for (int i = 0; i < 8; ++i)
#pragma unroll
    for (int j = 0; j < 6; ++j) acc[i][j] = (f32x4){0.f, 0.f, 0.f, 0.f};

  auto stA = [&](int bufi, int kt) {
    gl_lds16(Ab0 + (size_t)kt * 4096 + tid * 8, &As[bufi][0][0] + wv * 512);
    gl_lds16(Ab1 + (size_t)kt * 4096 + tid * 8, &As[bufi][1][0] + wv * 512);
  };
  auto stB = [&](int bufi, int kt) {
    gl_lds16(Bb0 + (size_t)kt * 4096 + tid * 8, &Bs[bufi][0][0] + wv * 512);
    gl_lds16(Bb1 + (size_t)kt * 4096 + tid * 8, &Bs[bufi][1][0] + wv * 512);
    gl_lds16(Bb2 + (size_t)kt * 4096 + tid * 8, &Bs[bufi][2][0] + wv * 512);
  };
  // B-fragment read: global col = wc*96 + j*16 (+llo); never straddles a third
  auto rdB = [&](int bufi, int j) -> f16x8 {
    int cg = wc * 96 + j * 16;
    return *(const f16x8*)(&Bs[bufi][cg >> 7][0] + (lhi * 128 + (cg & 127) + llo) * 8);
  };

  // prologue: tiles 0,1 in flight (10 loads/thread)
  stA(0, 0); stB(0, 0);
  stA(1, 1); stB(1, 1);

  for (int t = 0; t < KT; ++t) {
    const int buf = t % 3;
    const bool st = (t + 2 < KT);
    const int nb = (t + 2) % 3;

    if (t + 1 < KT) asm volatile("s_waitcnt vmcnt(5)" ::: "memory");
    else            asm volatile("s_waitcnt vmcnt(0)" ::: "memory");
    __builtin_amdgcn_s_barrier();   // tile t landed, collectively

    const f16* Ah = &As[buf][wr][0];
    f16x8 afr[8], bA, bB;

    // ---- pair 0: all 8 A-frags + B-frags 0,1; stage A(t+2) ----
#pragma unroll
    for (int i = 0; i < 8; ++i)
      afr[i] = *(const f16x8*)(Ah + (lhi * 128 + i * 16 + llo) * 8);
    bA = rdB(buf, 0); bB = rdB(buf, 1);
    if (st) stA(nb, t + 2);
    __builtin_amdgcn_s_barrier();
    asm volatile("s_waitcnt lgkmcnt(0)" ::: "memory");
    __builtin_amdgcn_s_setprio(1);
#pragma unroll
    for (int i = 0; i < 8; ++i) acc[i][0] = MFMA16(afr[i], bA, acc[i][0]);
#pragma unroll
    for (int i = 0; i < 8; ++i) acc[i][1] = MFMA16(afr[i], bB, acc[i][1]);
    __builtin_amdgcn_s_setprio(0);

    // ---- pair 1: B-frags 2,3; stage B(t+2) ----
    bA = rdB(buf, 2); bB = rdB(buf, 3);
    if (st) stB(nb, t + 2);
    __builtin_amdgcn_s_barrier();
    asm volatile("s_waitcnt lgkmcnt(0)" ::: "memory");
    __builtin_amdgcn_s_setprio(1);
#pragma unroll
    for (int i = 0; i < 8; ++i) acc[i][2] = MFMA16(afr[i], bA, acc[i][2]);
#pragma unroll
    for (int i = 0; i < 8; ++i) acc[i][3] = MFMA16(afr[i], bB, acc[i][3]);
    __builtin_amdgcn_s_setprio(0);

    // ---- pair 2: B-frags 4,5 ----
    bA = rdB(buf, 4); bB = rdB(buf, 5);
    __builtin_amdgcn_s_barrier();
    asm volatile("s_waitcnt lgkmcnt(0)" ::: "memory");
    __builtin_amdgcn_s_setprio(1);
#pragma unroll
    for (int i = 0; i < 8; ++i) acc[i][4] = MFMA16(afr[i], bA, acc[i][4]);
#pragma unroll
    for (int i = 0; i < 8; ++i) acc[i][5] = MFMA16(afr[i], bB, acc[i][5]);
    __builtin_amdgcn_s_setprio(0);
    // next tile-start barrier reconverges before buf reuse
  }

  // ---- epilogue: Q row-major / K,V attention-blocked scatter ----
#pragma unroll
  for (int j = 0; j < 6; ++j) {
    int col = bx * 384 + wc * 96 + j * 16 + llo;
    float bv = bias[col];
#pragma unroll
    for (int i = 0; i < 8; ++i) {
      int rowb = by * 256 + wr * 128 + i * 16 + lhi * 4;
      int region = col >> 11;  // 0:Q 1:K 2:V (per-element; 384-blocks straddle)
      if (region == 0) {
#pragma unroll
        for (int r = 0; r < 4; ++r)
          Qr[(size_t)(rowb + r) * HDIM + col] = (f16)(acc[i][j][r] + bv);
      } else if (region == 1) {
        int cK = col - HDIM;
        int hd = cK >> 7, d = cK & 127, g = d >> 3, dj = d & 7;
#pragma unroll
        for (int r = 0; r < 4; ++r) {
          int row = rowb + r;
          int b = row >> 11, s = row & 2047;
          int kt2 = s >> 6, key = s & 63;
          size_t addr = ((((size_t)(b * 16 + hd) * 32 + kt2) * 16 + g) * 64 + key) * 8 + dj;
          KB[addr] = (f16)(acc[i][j][r] + bv);
        }
      } else {
        int cV = col - 2 * HDIM;
        int hd = cV >> 7, d = cV & 127;
        int row = rowb;
        int b = row >> 11, s = row & 2047;
        int kt2 = s >> 6, key = s & 63;
        int kg = key >> 3, kj = key & 7;
        f16x4 pv = {(f16)(acc[i][j][0] + bv), (f16)(acc[i][j][1] + bv),
                    (f16)(acc[i][j][2] + bv), (f16)(acc[i][j][3] + bv)};
        size_t addr = ((((size_t)(b * 16 + hd) * 32 + kt2) * 8 + kg) * 128 + d) * 8 + kj;
        *(f16x4*)(VB + addr) = pv;
      }
    }
  }
}

// ---------------- out-proj GEMM: 256x256 tile, R3 phase-locked 4-buffer ------
// Grid 8x16x2 = 256 blocks = 1/CU, no tail.  Split-K by bz.  EXACT R3 form.
__global__ __launch_bounds__(512, 2) void gemm_out_kernel(const f16* __restrict__ Ablk,
                                                          const f16* __restrict__ Bblk,
                                                          f16* __restrict__ Cpart) {
  __shared__ f16 As[4][2][4096];
  __shared__ f16 Bs[4][2][4096];
  const int tid = threadIdx.x;
  const int lane = tid & 63, wv = tid >> 6;
  const int lhi = lane >> 4, llo = lane & 15;
  const int wr = wv >> 2, wc = wv & 3;

  // XCD-chunked swizzle
  int lin = blockIdx.x + 8 * (blockIdx.y + 16 * blockIdx.z);
  int xcd = lin & 7, slot = lin >> 3;        // slot in [0,32)
  int bx = slot & 7;
  int by = (xcd >> 1) * 4 + (slot >> 3);
  int bz = xcd & 1;

  const int KT = HDIM >> 5;                  // 64
  const int ntiles = KT >> 1;                // 32 per split
  const int t0 = bz * ntiles;

  const f16* Ab0 = Ablk + ((size_t)(2 * by)     * KT + t0) * 4096;
  const f16* Ab1 = Ablk + ((size_t)(2 * by + 1) * KT + t0) * 4096;
  const f16* Bb0 = Bblk + ((size_t)(2 * bx)     * KT + t0) * 4096;
  const f16* Bb1 = Bblk + ((size_t)(2 * bx + 1) * KT + t0) * 4096;

  f32x4 acc[8][4];
#pragma unroll
  for (int i = 0; i < 8; ++i)
#pragma unroll
    for (int j = 0; j < 4; ++j) acc[i][j] = (f32x4){0.f, 0.f, 0.f, 0.f};

  auto stA = [&](int bufi, int kt) {
    gl_lds16(Ab0 + (size_t)kt * 4096 + tid * 8, &As[bufi][0][0] + wv * 512);
    gl_lds16(Ab1 + (size_t)kt * 4096 + tid * 8, &As[bufi][1][0] + wv * 512);
  };
  auto stB = [&](int bufi, int kt) {
    gl_lds16(Bb0 + (size_t)kt * 4096 + tid * 8, &Bs[bufi][0][0] + wv * 512);
    gl_lds16(Bb1 + (size_t)kt * 4096 + tid * 8, &Bs[bufi][1][0] + wv * 512);
  };

#pragma unroll
  for (int u = 0; u < 3; ++u) { stA(u, u); stB(u, u); }

  for (int t = 0; t < ntiles; ++t) {
    const int buf = t & 3;
    const bool st = (t + 3 < ntiles);
    const int nb = (t + 3) & 3, ntile = t + 3;

    if (t + 2 < ntiles)      asm volatile("s_waitcnt vmcnt(8)" ::: "memory");
    else if (t + 1 < ntiles) asm volatile("s_waitcnt vmcnt(4)" ::: "memory");
    else                     asm volatile("s_waitcnt vmcnt(0)" ::: "memory");
    __builtin_amdgcn_s_barrier();

    const f16* Ah = &As[buf][wr][0];
    const f16* Bh = &Bs[buf][wc >> 1][0];
    f16x8 bfr[4], afr[4];

#pragma unroll
    for (int j = 0; j < 4; ++j)
      bfr[j] = *(const f16x8*)(Bh + (lhi * 128 + (wc & 1) * 64 + j * 16 + llo) * 8);
#pragma unroll
    for (int i = 0; i < 4; ++i)
      afr[i] = *(const f16x8*)(Ah + (lhi * 128 + i * 16 + llo) * 8);
    if (st) stA(nb, ntile);
    __builtin_amdgcn_s_barrier();
    asm volatile("s_waitcnt lgkmcnt(0)" ::: "memory");
    __builtin_amdgcn_s_setprio(1);
#pragma unroll
    for (int i = 0; i < 4; ++i)
#pragma unroll
      for (int j = 0; j < 4; ++j) acc[i][j] = MFMA16(afr[i], bfr[j], acc[i][j]);
    __builtin_amdgcn_s_setprio(0);
    __builtin_amdgcn_s_barrier();

#pragma unroll
    for (int i = 0; i < 4; ++i)
      afr[i] = *(const f16x8*)(Ah + (lhi * 128 + (i + 4) * 16 + llo) * 8);
    if (st) stB(nb, ntile);
    __builtin_amdgcn_s_barrier();
    asm volatile("s_waitcnt lgkmcnt(0)" ::: "memory");
    __builtin_amdgcn_s_setprio(1);
#pragma unroll
    for (int i = 0; i < 4; ++i)
#pragma unroll
      for (int j = 0; j < 4; ++j) acc[i + 4][j] = MFMA16(afr[i], bfr[j], acc[i + 4][j]);
    __builtin_amdgcn_s_setprio(0);
  }

#pragma unroll
  for (int j = 0; j < 4; ++j) {
    int col = bx * 256 + wc * 64 + j * 16 + llo;
#pragma unroll
    for (int i = 0; i < 8; ++i) {
      int rowb = by * 256 + wr * 128 + i * 16 + lhi * 4;
      size_t zoff = (size_t)bz * MROWS * HDIM;
#pragma unroll
      for (int r = 0; r < 4; ++r)
        Cpart[zoff + (size_t)(rowb + r) * HDIM + col] = (f16)acc[i][j][r];
    }
  }
}

// ---------------- bias + split-K merge -> f32 out ----------------
__global__ __launch_bounds__(256) void merge_out_kernel(const f16* __restrict__ Cpart,
                                                        const float* __restrict__ bias,
                                                        float* __restrict__ out) {
  int t = blockIdx.x * 256 + threadIdx.x;   // MROWS*HDIM/8 threads
  int col8 = (t & 255) * 8;
  int row = t >> 8;
  size_t base = (size_t)row * HDIM + col8;
  const size_t MN = (size_t)MROWS * HDIM;
  f16x8 a = *(const f16x8*)(Cpart + base);
  f16x8 b = *(const f16x8*)(Cpart + MN + base);
  float4 b0 = *(const float4*)(bias + col8);
  float4 b1 = *(const float4*)(bias + col8 + 4);
  float4 o0 = {(float)a[0] + (float)b[0] + b0.x, (float)a[1] + (float)b[1] + b0.y,
               (float)a[2] + (float)b[2] + b0.z, (float)a[3] + (float)b[3] + b0.w};
  float4 o1 = {(float)a[4] + (float)b[4] + b1.x, (float)a[5] + (float)b[5] + b1.y,
               (float)a[6] + (float)b[6] + b1.z, (float)a[7] + (float)b[7] + b1.w};
  *(float4*)(out + base) = o0;
  *(float4*)(out + base + 4) = o1;
}

// ---------------- causal flash attention: barrier-free, L2-direct K/V --------
// K/V per (b,h) is 512 KB; the XCD swizzle keeps ~4 heads (~2 MB) per XCD's
// 4 MiB L2, so LDS staging is pure overhead (m169 regime).  MFMA operands are
// read straight from the blocked KB/VB layouts (32 lanes x 16 B contiguous =
// coalesced); this deletes both per-tile __syncthreads + the vmcnt(0) drains,
// and waves free-run with a per-wave causal bound.  Only Ps (per-wave P
// staging, 18.4 KB) remains in LDS.
__global__ __launch_bounds__(256) void attn_kernel(const f16* __restrict__ Qr,
                                                   const f16* __restrict__ KB,
                                                   const f16* __restrict__ VB,
                                                   f16* __restrict__ Opart,
                                                   float* __restrict__ Lpart) {
  __shared__ f16 Ps[4][32 * 72];   // per-wave [q(32)][key(64)] stride 72

  int tid = threadIdx.x, lane = tid & 63, w = tid >> 6;
  int l5 = lane & 31, hl = lane >> 5;

  // XCD-chunked swizzle: 4 bh x 24 gx per XCD (KB/VB panel locality in L2)
  int lin0 = blockIdx.x + 24 * blockIdx.y;
  int xcd0 = lin0 & 7, slot0 = lin0 >> 3;   // slot0 in [0,96)
  int bh = xcd0 * 4 + slot0 / 24;
  int gx = slot0 % 24;

  int b = bh >> 4, hd = bh & 15;
  int qt, kt0, kt1, slot;
  if (gx < 8) { qt = gx; slot = 0; kt0 = 0; kt1 = 2 * qt + 2; }
  else {
    qt = 8 + ((gx - 8) >> 1); slot = (gx - 8) & 1;
    kt0 = slot ? (qt + 1) : 0;
    kt1 = slot ? (2 * qt + 2) : (qt + 1);
  }

  int qbase = qt * 128 + w * 32;
  int qrow = qbase + l5;

  // per-wave causal bound: last key-tile this wave touches
  int ktw = (qbase + 31) / 64 + 1;
  if (ktw > kt1) ktw = kt1;

  const f16* qp = Qr + (size_t)(b * S_LEN + qrow) * HDIM + hd * DHEAD + hl * 8;
  f16x8 qf[8];
#pragma unroll
  for (int s8 = 0; s8 < 8; ++s8) qf[s8] = *(const f16x8*)(qp + s8 * 16);

  f32x16 oac[4];
#pragma unroll
  for (int mt = 0; mt < 4; ++mt)
#pragma unroll
    for (int r = 0; r < 16; ++r) oac[mt][r] = 0.f;
  float rs = 0.f;

  const float C1 = 0.12752747419986393f;   // log2(e)/sqrt(128)
  const float C2 = 11.541560327111708f;    // 8 * log2(e)

  const f16* KBb = KB + (size_t)bh * 32 * 8192;
  const f16* VBb = VB + (size_t)bh * 32 * 8192;

  for (int kt = kt0; kt < ktw; ++kt) {
    const f16* Kt = KBb + (size_t)kt * 8192;   // [g(16)][key(64)][8]
    const f16* Vt = VBb + (size_t)kt * 8192;   // [kg(8)][d(128)][8]

    f32x16 sac[2];
#pragma unroll
    for (int mt = 0; mt < 2; ++mt)
#pragma unroll
      for (int r = 0; r < 16; ++r) sac[mt][r] = 0.f;
#pragma unroll
    for (int s8 = 0; s8 < 8; ++s8) {
#pragma unroll
      for (int mt = 0; mt < 2; ++mt) {
        f16x8 kf = *(const f16x8*)(Kt + ((s8 * 2 + hl) * 64 + mt * 32 + l5) * 8);
        sac[mt] = MFMA32(kf, qf[s8], sac[mt]);
      }
    }

    bool diag = (kt * 64 + 63 > qbase);
#pragma unroll
    for (int mt = 0; mt < 2; ++mt) {
#pragma unroll
      for (int g4 = 0; g4 < 4; ++g4) {
        f16x4 pk;
#pragma unroll
        for (int r = 0; r < 4; ++r) {
          int keyl = mt * 32 + g4 * 8 + hl * 4 + r;
          float p = __builtin_amdgcn_exp2f(fmaf(sac[mt][g4 * 4 + r], C1, -C2));
          if (diag && (kt * 64 + keyl > qrow)) p = 0.f;
          rs += p;
          pk[r] = (f16)p;
        }
        *(f16x4*)(&Ps[w][l5 * 72 + mt * 32 + g4 * 8 + hl * 4]) = pk;
      }
    }
    asm volatile("s_waitcnt lgkmcnt(0)" ::: "memory");  // same-wave P write->read

#pragma unroll
    for (int ks = 0; ks < 4; ++ks) {
      f16x8 pf = *(const f16x8*)(&Ps[w][l5 * 72 + ks * 16 + hl * 8]);
#pragma unroll
      for (int mt = 0; mt < 4; ++mt) {
        f16x8 vf = *(const f16x8*)(Vt + ((ks * 2 + hl) * 128 + mt * 32 + l5) * 8);
        oac[mt] = MFMA32(vf, pf, oac[mt]);
      }
    }
  }

  float lsum = rs + __shfl_xor(rs, 32, 64);
  size_t ob = ((size_t)slot * 32 + bh) * S_LEN * DHEAD + (size_t)qrow * DHEAD;
#pragma unroll
  for (int mt = 0; mt < 4; ++mt) {
#pragma unroll
    for (int g4 = 0; g4 < 4; ++g4) {
      int d = mt * 32 + g4 * 8 + hl * 4;
      f16x4 ov = {(f16)oac[mt][g4 * 4 + 0], (f16)oac[mt][g4 * 4 + 1],
                  (f16)oac[mt][g4 * 4 + 2], (f16)oac[mt][g4 * 4 + 3]};
      *(f16x4*)(Opart + ob + d) = ov;
    }
  }
  if (hl == 0) Lpart[((size_t)slot * 32 + bh) * S_LEN + qrow] = lsum;
}

// ---------------- merge attn partials -> CTX blocked f16 ----------------
__global__ __launch_bounds__(256) void merge_kernel(const f16* __restrict__ Opart,
                                                    const float* __restrict__ Lpart,
                                                    f16* __restrict__ CTXb) {
  int t = blockIdx.x * 256 + threadIdx.x;  // 32*2048*16 threads
  int d8 = (t & 15) * 8;
  int q = (t >> 4) & 2047;
  int bh = t >> 15;
  int b = bh >> 4, hd = bh & 15;
  int ns = ((q >> 7) >= 8) ? 2 : 1;
  size_t o0 = ((size_t)bh * S_LEN + q) * DHEAD + d8;
  const size_t OSLOT = (size_t)32 * S_LEN * DHEAD;
  float l = Lpart[(size_t)bh * S_LEN + q];
  f16x8 a = *(const f16x8*)(Opart + o0);
  float acc[8];
#pragma unroll
  for (int j = 0; j < 8; ++j) acc[j] = (float)a[j];
  if (ns == 2) {
    l += Lpart[OSLOT / DHEAD + (size_t)bh * S_LEN + q];
    f16x8 a2 = *(const f16x8*)(Opart + OSLOT + o0);
#pragma unroll
    for (int j = 0; j < 8; ++j) acc[j] += (float)a2[j];
  }
  float inv = 1.0f / l;
  f16x8 o;
#pragma unroll
  for (int j = 0; j < 8; ++j) o[j] = (f16)(acc[j] * inv);
  // blocked write: row = b*S+q, col = hd*128+d8  (K = HDIM, KT = 64)
  int row = b * S_LEN + q;
  int col = hd * DHEAD + d8;
  int rt = row >> 7, rr = row & 127;
  int kt = col >> 5, kc = (col >> 3) & 3;
  *(f16x8*)(CTXb + ((size_t)rt * 64 + kt) * 4096 + (kc * 128 + rr) * 8) = o;
}

// ---------------- launch ----------------
extern "C" void kernel_launch(void* const* d_in, const int* in_sizes, int n_in,
                              void* d_out, int out_size, void* d_ws, size_t ws_size,
                              hipStream_t stream) {
  const float* X    = (const float*)d_in[0];
  const float* Wqkv = (const float*)d_in[2];
  const float* bqkv = (const float*)d_in[3];
  const float* Wout = (const float*)d_in[4];
  const float* bout = (const float*)d_in[5];
  float* out = (float*)d_out;

  char* ws = (char*)d_ws;
  f16* Xb    = (f16*)ws;  ws += (size_t)MROWS * HDIM * sizeof(f16);    // 16 MiB (reused as CTXb)
  f16* Wqkvb = (f16*)ws;  ws += (size_t)QKVN * HDIM * sizeof(f16);     // 24 MiB
  f16* Woutb = (f16*)ws;  ws += (size_t)HDIM * HDIM * sizeof(f16);     // 8 MiB
  f16* Qr    = (f16*)ws;  ws += (size_t)MROWS * HDIM * sizeof(f16);    // 16 MiB
  f16* KB    = (f16*)ws;  ws += (size_t)32 * 32 * 8192 * sizeof(f16);  // 16 MiB
  f16* VB    = (f16*)ws;  ws += (size_t)32 * 32 * 8192 * sizeof(f16);  // 16 MiB
  f16* Opart = (f16*)ws;  ws += (size_t)2 * 32 * S_LEN * DHEAD * sizeof(f16);  // 32 MiB
  float* Lpart = (float*)ws;  ws += (size_t)2 * 32 * S_LEN * sizeof(float);    // 512 KiB
  f16* CTXb  = Xb;        // Xb dead after QKV GEMM
  f16* Cpart = Opart;     // Opart dead after merge_kernel; 2*M*N*2B = 32 MiB fits

  prep_kernel<<<6144, 256, 0, stream>>>(X, Xb, Wqkv, Wqkvb, Wout, Woutb);

  // QKV GEMM: 256x384 tiles -> 16x16 = 256 blocks = exactly 1/CU, no tail
  gemm_qkv_kernel<<<dim3(QKVN / 384, MROWS / 256), 512, 0, stream>>>(
      Xb, Wqkvb, bqkv, Qr, KB, VB);

  attn_kernel<<<dim3(24, 32), 256, 0, stream>>>(Qr, KB, VB, Opart, Lpart);

  merge_kernel<<<(32 * S_LEN * 16) / 256, 256, 0, stream>>>(Opart, Lpart, CTXb);

  // out-proj: split-K 2 -> 8x16x2 = 256 blocks = exactly 1/CU, no tail
  gemm_out_kernel<<<dim3(HDIM / 256, MROWS / 256, 2), 512, 0, stream>>>(
      CTXb, Woutb, Cpart);

  merge_out_kernel<<<(MROWS * HDIM / 8) / 256, 256, 0, stream>>>(Cpart, bout, out);
}

// Round 6
// 379.278 us; speedup vs baseline: 1.4026x; 1.4026x over previous
//
#include <hip/hip_runtime.h>

#define S_LEN 2048
#define HDIM  2048
#define NHEADS 16
#define DHEAD 128
#define BATCH 2
#define MROWS (BATCH * S_LEN)   // 4096
#define QKVN  (3 * HDIM)        // 6144

typedef _Float16 f16;
typedef _Float16 f16x8 __attribute__((ext_vector_type(8)));
typedef _Float16 f16x4 __attribute__((ext_vector_type(4)));
typedef float    f32x4 __attribute__((ext_vector_type(4)));
typedef float    f32x16 __attribute__((ext_vector_type(16)));

typedef const __attribute__((address_space(1))) void* gas_ptr;
typedef __attribute__((address_space(3))) void*       las_ptr;

#define MFMA16(a, b, c)  __builtin_amdgcn_mfma_f32_16x16x32_f16(a, b, c, 0, 0, 0)
#define MFMA32(a, b, c)  __builtin_amdgcn_mfma_f32_32x32x16_f16(a, b, c, 0, 0, 0)

__device__ __forceinline__ void gl_lds16(const f16* g, f16* lds_wave_base) {
  __builtin_amdgcn_global_load_lds((gas_ptr)g, (las_ptr)lds_wave_base, 16, 0, 0);
}

// Blocked tile layout for GEMM operands: tile (rt, kt) of logical [rows][K] f16,
// 128 rows x 32 k, stored as [kc(4)][r(128)][8] (8 KB) at tile index rt*(K/32)+kt.

// ---------------- fused prep: X cvt + both weight transposes ------------------
__device__ __forceinline__ void transpose_tile(const float* __restrict__ W,
                                               f16* __restrict__ Wb,
                                               int K, int N, int k0, int n0,
                                               float* tile /*[64][65]*/) {
  int tr = threadIdx.x >> 4;
  int tc = (threadIdx.x & 15) * 4;
  int KT = K >> 5;
#pragma unroll
  for (int rr = 0; rr < 4; ++rr) {
    int r = rr * 16 + tr;
    float4 v = *(const float4*)(W + (size_t)(k0 + r) * N + n0 + tc);
    tile[r * 65 + tc + 0] = v.x; tile[r * 65 + tc + 1] = v.y;
    tile[r * 65 + tc + 2] = v.z; tile[r * 65 + tc + 3] = v.w;
  }
  __syncthreads();
#pragma unroll
  for (int rr = 0; rr < 4; ++rr) {
    int r = rr * 16 + tr;
    int n = n0 + r;
    int kBase = k0 + tc;
    f16x4 o;
#pragma unroll
    for (int c = 0; c < 4; ++c) o[c] = (f16)tile[(tc + c) * 65 + r];
    int nt = n >> 7, nn = n & 127;
    int kt = kBase >> 5, kc = (kBase >> 3) & 3, j = kBase & 7;
    *(f16x4*)(Wb + ((size_t)nt * KT + kt) * 4096 + (kc * 128 + nn) * 8 + j) = o;
  }
}

__global__ __launch_bounds__(256) void prep_kernel(const float* __restrict__ X,
                                                   f16* __restrict__ Xb,
                                                   const float* __restrict__ Wqkv,
                                                   f16* __restrict__ Wqkvb,
                                                   const float* __restrict__ Wout,
                                                   f16* __restrict__ Woutb) {
  __shared__ float tile[64 * 65];
  int bz = blockIdx.x;
  if (bz < 2048) {
    int kt = bz & 63, rt = bz >> 6;
    int t = threadIdx.x;
    int m = t >> 1, half = t & 1;
    const float* src = X + (size_t)(rt * 128 + m) * HDIM + kt * 32 + half * 16;
    float4 v0 = ((const float4*)src)[0];
    float4 v1 = ((const float4*)src)[1];
    float4 v2 = ((const float4*)src)[2];
    float4 v3 = ((const float4*)src)[3];
    f16x8 a = {(f16)v0.x, (f16)v0.y, (f16)v0.z, (f16)v0.w,
               (f16)v1.x, (f16)v1.y, (f16)v1.z, (f16)v1.w};
    f16x8 b = {(f16)v2.x, (f16)v2.y, (f16)v2.z, (f16)v2.w,
               (f16)v3.x, (f16)v3.y, (f16)v3.z, (f16)v3.w};
    f16* dst = Xb + ((size_t)rt * 64 + kt) * 4096 + ((half * 2) * 128 + m) * 8;
    *(f16x8*)dst = a;
    *(f16x8*)(dst + 1024) = b;
  } else if (bz < 5120) {
    int u = bz - 2048;                 // 96 n-blocks x 32 k-blocks
    int nx = u % 96, ky = u / 96;
    transpose_tile(Wqkv, Wqkvb, HDIM, QKVN, ky * 64, nx * 64, tile);
  } else {
    int u = bz - 5120;                 // 32 x 32
    int nx = u & 31, ky = u >> 5;
    transpose_tile(Wout, Woutb, HDIM, HDIM, ky * 64, nx * 64, tile);
  }
}

// ---------------- QKV GEMM: 256x384 tile, 8-wave, 3-buffer pipeline ----------
// EXACT R3 form (measured 114us): phase-locked cadence reads->barrier->
// lgkmcnt(0)->setprio 16-MFMA clusters; R4's rebalance/drain-removal regressed
// (137us) -- do not touch this schedule.
__global__ __launch_bounds__(512, 2) void gemm_qkv_kernel(const f16* __restrict__ Ablk,
                                                          const f16* __restrict__ Bblk,
                                                          const float* __restrict__ bias,
                                                          f16* __restrict__ Qr,
                                                          f16* __restrict__ KB,
                                                          f16* __restrict__ VB) {
  __shared__ f16 As[3][2][4096];   // [buf][row-half 128][blocked 128x32 tile]
  __shared__ f16 Bs[3][3][4096];   // [buf][col-third 128][blocked 128x32 tile]
  const int tid = threadIdx.x;
  const int lane = tid & 63, wv = tid >> 6;
  const int lhi = lane >> 4, llo = lane & 15;
  const int wr = wv >> 2, wc = wv & 3;       // 2M x 4N wave grid; wave owns 128x96

  // XCD-chunked swizzle: each XCD gets a 4bx x 8by cell (panel L2 locality)
  int lin = blockIdx.x + 16 * blockIdx.y;
  int xcd = lin & 7, slot = lin >> 3;        // slot in [0,32)
  int bx = (xcd & 3) * 4 + (slot & 3);
  int by = (xcd >> 2) * 8 + (slot >> 2);

  const int KT = HDIM >> 5;                  // 64 K-tiles
  const f16* Ab0 = Ablk + (size_t)(2 * by)     * KT * 4096;
  const f16* Ab1 = Ablk + (size_t)(2 * by + 1) * KT * 4096;
  const f16* Bb0 = Bblk + (size_t)(3 * bx)     * KT * 4096;
  const f16* Bb1 = Bblk + (size_t)(3 * bx + 1) * KT * 4096;
  const f16* Bb2 = Bblk + (size_t)(3 * bx + 2) * KT * 4096;

  f32x4 acc[8][6];
#pragma unroll
  for (int i = 0; i < 8; ++i)
#pragma unroll
    for (int j = 0; j < 6; ++j) acc[i][j] = (f32x4){0.f, 0.f, 0.f, 0.f};

  auto stA = [&](int bufi, int kt) {
    gl_lds16(Ab0 + (size_t)kt * 4096 + tid * 8, &As[bufi][0][0] + wv * 512);
    gl_lds16(Ab1 + (size_t)kt * 4096 + tid * 8, &As[bufi][1][0] + wv * 512);
  };
  auto stB = [&](int bufi, int kt) {
    gl_lds16(Bb0 + (size_t)kt * 4096 + tid * 8, &Bs[bufi][0][0] + wv * 512);
    gl_lds16(Bb1 + (size_t)kt * 4096 + tid * 8, &Bs[bufi][1][0] + wv * 512);
    gl_lds16(Bb2 + (size_t)kt * 4096 + tid * 8, &Bs[bufi][2][0] + wv * 512);
  };
  // B-fragment read: global col = wc*96 + j*16 (+llo); never straddles a third
  auto rdB = [&](int bufi, int j) -> f16x8 {
    int cg = wc * 96 + j * 16;
    return *(const f16x8*)(&Bs[bufi][cg >> 7][0] + (lhi * 128 + (cg & 127) + llo) * 8);
  };

  // prologue: tiles 0,1 in flight (10 loads/thread)
  stA(0, 0); stB(0, 0);
  stA(1, 1); stB(1, 1);

  for (int t = 0; t < KT; ++t) {
    const int buf = t % 3;
    const bool st = (t + 2 < KT);
    const int nb = (t + 2) % 3;

    if (t + 1 < KT) asm volatile("s_waitcnt vmcnt(5)" ::: "memory");
    else            asm volatile("s_waitcnt vmcnt(0)" ::: "memory");
    __builtin_amdgcn_s_barrier();   // tile t landed, collectively

    const f16* Ah = &As[buf][wr][0];
    f16x8 afr[8], bA, bB;

    // ---- pair 0: all 8 A-frags + B-frags 0,1; stage A(t+2) ----
#pragma unroll
    for (int i = 0; i < 8; ++i)
      afr[i] = *(const f16x8*)(Ah + (lhi * 128 + i * 16 + llo) * 8);
    bA = rdB(buf, 0); bB = rdB(buf, 1);
    if (st) stA(nb, t + 2);
    __builtin_amdgcn_s_barrier();
    asm volatile("s_waitcnt lgkmcnt(0)" ::: "memory");
    __builtin_amdgcn_s_setprio(1);
#pragma unroll
    for (int i = 0; i < 8; ++i) acc[i][0] = MFMA16(afr[i], bA, acc[i][0]);
#pragma unroll
    for (int i = 0; i < 8; ++i) acc[i][1] = MFMA16(afr[i], bB, acc[i][1]);
    __builtin_amdgcn_s_setprio(0);

    // ---- pair 1: B-frags 2,3; stage B(t+2) ----
    bA = rdB(buf, 2); bB = rdB(buf, 3);
    if (st) stB(nb, t + 2);
    __builtin_amdgcn_s_barrier();
    asm volatile("s_waitcnt lgkmcnt(0)" ::: "memory");
    __builtin_amdgcn_s_setprio(1);
#pragma unroll
    for (int i = 0; i < 8; ++i) acc[i][2] = MFMA16(afr[i], bA, acc[i][2]);
#pragma unroll
    for (int i = 0; i < 8; ++i) acc[i][3] = MFMA16(afr[i], bB, acc[i][3]);
    __builtin_amdgcn_s_setprio(0);

    // ---- pair 2: B-frags 4,5 ----
    bA = rdB(buf, 4); bB = rdB(buf, 5);
    __builtin_amdgcn_s_barrier();
    asm volatile("s_waitcnt lgkmcnt(0)" ::: "memory");
    __builtin_amdgcn_s_setprio(1);
#pragma unroll
    for (int i = 0; i < 8; ++i) acc[i][4] = MFMA16(afr[i], bA, acc[i][4]);
#pragma unroll
    for (int i = 0; i < 8; ++i) acc[i][5] = MFMA16(afr[i], bB, acc[i][5]);
    __builtin_amdgcn_s_setprio(0);
    // next tile-start barrier reconverges before buf reuse
  }

  // ---- epilogue: Q row-major / K,V attention-blocked scatter ----
#pragma unroll
  for (int j = 0; j < 6; ++j) {
    int col = bx * 384 + wc * 96 + j * 16 + llo;
    float bv = bias[col];
#pragma unroll
    for (int i = 0; i < 8; ++i) {
      int rowb = by * 256 + wr * 128 + i * 16 + lhi * 4;
      int region = col >> 11;  // 0:Q 1:K 2:V (per-element; 384-blocks straddle)
      if (region == 0) {
#pragma unroll
        for (int r = 0; r < 4; ++r)
          Qr[(size_t)(rowb + r) * HDIM + col] = (f16)(acc[i][j][r] + bv);
      } else if (region == 1) {
        int cK = col - HDIM;
        int hd = cK >> 7, d = cK & 127, g = d >> 3, dj = d & 7;
#pragma unroll
        for (int r = 0; r < 4; ++r) {
          int row = rowb + r;
          int b = row >> 11, s = row & 2047;
          int kt2 = s >> 6, key = s & 63;
          size_t addr = ((((size_t)(b * 16 + hd) * 32 + kt2) * 16 + g) * 64 + key) * 8 + dj;
          KB[addr] = (f16)(acc[i][j][r] + bv);
        }
      } else {
        int cV = col - 2 * HDIM;
        int hd = cV >> 7, d = cV & 127;
        int row = rowb;
        int b = row >> 11, s = row & 2047;
        int kt2 = s >> 6, key = s & 63;
        int kg = key >> 3, kj = key & 7;
        f16x4 pv = {(f16)(acc[i][j][0] + bv), (f16)(acc[i][j][1] + bv),
                    (f16)(acc[i][j][2] + bv), (f16)(acc[i][j][3] + bv)};
        size_t addr = ((((size_t)(b * 16 + hd) * 32 + kt2) * 8 + kg) * 128 + d) * 8 + kj;
        *(f16x4*)(VB + addr) = pv;
      }
    }
  }
}

// ---------------- out-proj GEMM: 256x256 tile, R3 phase-locked 4-buffer ------
// Grid 8x16x2 = 256 blocks = 1/CU, no tail.  Split-K by bz.  EXACT R3 form.
__global__ __launch_bounds__(512, 2) void gemm_out_kernel(const f16* __restrict__ Ablk,
                                                          const f16* __restrict__ Bblk,
                                                          f16* __restrict__ Cpart) {
  __shared__ f16 As[4][2][4096];
  __shared__ f16 Bs[4][2][4096];
  const int tid = threadIdx.x;
  const int lane = tid & 63, wv = tid >> 6;
  const int lhi = lane >> 4, llo = lane & 15;
  const int wr = wv >> 2, wc = wv & 3;

  // XCD-chunked swizzle
  int lin = blockIdx.x + 8 * (blockIdx.y + 16 * blockIdx.z);
  int xcd = lin & 7, slot = lin >> 3;        // slot in [0,32)
  int bx = slot & 7;
  int by = (xcd >> 1) * 4 + (slot >> 3);
  int bz = xcd & 1;

  const int KT = HDIM >> 5;                  // 64
  const int ntiles = KT >> 1;                // 32 per split
  const int t0 = bz * ntiles;

  const f16* Ab0 = Ablk + ((size_t)(2 * by)     * KT + t0) * 4096;
  const f16* Ab1 = Ablk + ((size_t)(2 * by + 1) * KT + t0) * 4096;
  const f16* Bb0 = Bblk + ((size_t)(2 * bx)     * KT + t0) * 4096;
  const f16* Bb1 = Bblk + ((size_t)(2 * bx + 1) * KT + t0) * 4096;

  f32x4 acc[8][4];
#pragma unroll
  for (int i = 0; i < 8; ++i)
#pragma unroll
    for (int j = 0; j < 4; ++j) acc[i][j] = (f32x4){0.f, 0.f, 0.f, 0.f};

  auto stA = [&](int bufi, int kt) {
    gl_lds16(Ab0 + (size_t)kt * 4096 + tid * 8, &As[bufi][0][0] + wv * 512);
    gl_lds16(Ab1 + (size_t)kt * 4096 + tid * 8, &As[bufi][1][0] + wv * 512);
  };
  auto stB = [&](int bufi, int kt) {
    gl_lds16(Bb0 + (size_t)kt * 4096 + tid * 8, &Bs[bufi][0][0] + wv * 512);
    gl_lds16(Bb1 + (size_t)kt * 4096 + tid * 8, &Bs[bufi][1][0] + wv * 512);
  };

#pragma unroll
  for (int u = 0; u < 3; ++u) { stA(u, u); stB(u, u); }

  for (int t = 0; t < ntiles; ++t) {
    const int buf = t & 3;
    const bool st = (t + 3 < ntiles);
    const int nb = (t + 3) & 3, ntile = t + 3;

    if (t + 2 < ntiles)      asm volatile("s_waitcnt vmcnt(8)" ::: "memory");
    else if (t + 1 < ntiles) asm volatile("s_waitcnt vmcnt(4)" ::: "memory");
    else                     asm volatile("s_waitcnt vmcnt(0)" ::: "memory");
    __builtin_amdgcn_s_barrier();

    const f16* Ah = &As[buf][wr][0];
    const f16* Bh = &Bs[buf][wc >> 1][0];
    f16x8 bfr[4], afr[4];

#pragma unroll
    for (int j = 0; j < 4; ++j)
      bfr[j] = *(const f16x8*)(Bh + (lhi * 128 + (wc & 1) * 64 + j * 16 + llo) * 8);
#pragma unroll
    for (int i = 0; i < 4; ++i)
      afr[i] = *(const f16x8*)(Ah + (lhi * 128 + i * 16 + llo) * 8);
    if (st) stA(nb, ntile);
    __builtin_amdgcn_s_barrier();
    asm volatile("s_waitcnt lgkmcnt(0)" ::: "memory");
    __builtin_amdgcn_s_setprio(1);
#pragma unroll
    for (int i = 0; i < 4; ++i)
#pragma unroll
      for (int j = 0; j < 4; ++j) acc[i][j] = MFMA16(afr[i], bfr[j], acc[i][j]);
    __builtin_amdgcn_s_setprio(0);
    __builtin_amdgcn_s_barrier();

#pragma unroll
    for (int i = 0; i < 4; ++i)
      afr[i] = *(const f16x8*)(Ah + (lhi * 128 + (i + 4) * 16 + llo) * 8);
    if (st) stB(nb, ntile);
    __builtin_amdgcn_s_barrier();
    asm volatile("s_waitcnt lgkmcnt(0)" ::: "memory");
    __builtin_amdgcn_s_setprio(1);
#pragma unroll
    for (int i = 0; i < 4; ++i)
#pragma unroll
      for (int j = 0; j < 4; ++j) acc[i + 4][j] = MFMA16(afr[i], bfr[j], acc[i + 4][j]);
    __builtin_amdgcn_s_setprio(0);
  }

#pragma unroll
  for (int j = 0; j < 4; ++j) {
    int col = bx * 256 + wc * 64 + j * 16 + llo;
#pragma unroll
    for (int i = 0; i < 8; ++i) {
      int rowb = by * 256 + wr * 128 + i * 16 + lhi * 4;
      size_t zoff = (size_t)bz * MROWS * HDIM;
#pragma unroll
      for (int r = 0; r < 4; ++r)
        Cpart[zoff + (size_t)(rowb + r) * HDIM + col] = (f16)acc[i][j][r];
    }
  }
}

// ---------------- bias + split-K merge -> f32 out ----------------
__global__ __launch_bounds__(256) void merge_out_kernel(const f16* __restrict__ Cpart,
                                                        const float* __restrict__ bias,
                                                        float* __restrict__ out) {
  int t = blockIdx.x * 256 + threadIdx.x;   // MROWS*HDIM/8 threads
  int col8 = (t & 255) * 8;
  int row = t >> 8;
  size_t base = (size_t)row * HDIM + col8;
  const size_t MN = (size_t)MROWS * HDIM;
  f16x8 a = *(const f16x8*)(Cpart + base);
  f16x8 b = *(const f16x8*)(Cpart + MN + base);
  float4 b0 = *(const float4*)(bias + col8);
  float4 b1 = *(const float4*)(bias + col8 + 4);
  float4 o0 = {(float)a[0] + (float)b[0] + b0.x, (float)a[1] + (float)b[1] + b0.y,
               (float)a[2] + (float)b[2] + b0.z, (float)a[3] + (float)b[3] + b0.w};
  float4 o1 = {(float)a[4] + (float)b[4] + b1.x, (float)a[5] + (float)b[5] + b1.y,
               (float)a[6] + (float)b[6] + b1.z, (float)a[7] + (float)b[7] + b1.w};
  *(float4*)(out + base) = o0;
  *(float4*)(out + base + 4) = o1;
}

// ---------------- causal flash attention: R3 staged form + T14 async-STAGE ---
// R5's L2-direct reads regressed 3.3x (dependent vmem latency on the MFMA
// critical path, no TLP to hide it) -- staging reverted.  T14 applied: K/V of
// tile t+1 are global-loaded into REGISTERS during tile-t compute (latency
// hides under ~48 MFMA + softmax), then ds_written at the top of tile t+1
// between the two __syncthreads.  LDS stays 51.2 KB -> 3 blocks/CU.
__global__ __launch_bounds__(256, 3) void attn_kernel(const f16* __restrict__ Qr,
                                                      const f16* __restrict__ KB,
                                                      const f16* __restrict__ VB,
                                                      f16* __restrict__ Opart,
                                                      float* __restrict__ Lpart) {
  __shared__ f16 Ks[1024 * 8];     // [g(16)][key(64)][8]
  __shared__ f16 Vs[1024 * 8];     // [kg(8)][d(128)][8]
  __shared__ f16 Ps[4][32 * 72];   // per-wave [q(32)][key(64)] stride 72

  int tid = threadIdx.x, lane = tid & 63, w = tid >> 6;
  int l5 = lane & 31, hl = lane >> 5;

  // XCD-chunked swizzle: 4 bh x 24 gx per XCD (KB/VB panel locality in L2)
  int lin0 = blockIdx.x + 24 * blockIdx.y;
  int xcd0 = lin0 & 7, slot0 = lin0 >> 3;   // slot0 in [0,96)
  int bh = xcd0 * 4 + slot0 / 24;
  int gx = slot0 % 24;

  int b = bh >> 4, hd = bh & 15;
  int qt, kt0, kt1, slot;
  if (gx < 8) { qt = gx; slot = 0; kt0 = 0; kt1 = 2 * qt + 2; }
  else {
    qt = 8 + ((gx - 8) >> 1); slot = (gx - 8) & 1;
    kt0 = slot ? (qt + 1) : 0;
    kt1 = slot ? (2 * qt + 2) : (qt + 1);
  }

  int qbase = qt * 128 + w * 32;
  int qrow = qbase + l5;

  const f16* qp = Qr + (size_t)(b * S_LEN + qrow) * HDIM + hd * DHEAD + hl * 8;
  f16x8 qf[8];
#pragma unroll
  for (int s8 = 0; s8 < 8; ++s8) qf[s8] = *(const f16x8*)(qp + s8 * 16);

  f32x16 oac[4];
#pragma unroll
  for (int mt = 0; mt < 4; ++mt)
#pragma unroll
    for (int r = 0; r < 16; ++r) oac[mt][r] = 0.f;
  float rs = 0.f;

  const float C1 = 0.12752747419986393f;   // log2(e)/sqrt(128)
  const float C2 = 11.541560327111708f;    // 8 * log2(e)

  const f16* KBb = KB + (size_t)bh * 32 * 8192;
  const f16* VBb = VB + (size_t)bh * 32 * 8192;

  // T14 register staging: 4 K-frags + 4 V-frags per thread (64 B each)
  f16x8 kreg[4], vreg[4];
  auto ldregs = [&](int kt) {
    const f16* Kt = KBb + (size_t)kt * 8192;
    const f16* Vt = VBb + (size_t)kt * 8192;
#pragma unroll
    for (int c = 0; c < 4; ++c) {
      int u0 = w * 256 + c * 64 + lane;
      kreg[c] = *(const f16x8*)(Kt + (size_t)u0 * 8);
      vreg[c] = *(const f16x8*)(Vt + (size_t)u0 * 8);
    }
  };

  ldregs(kt0);   // prologue

  for (int kt = kt0; kt < kt1; ++kt) {
    __syncthreads();   // readers of previous tile done
    {
#pragma unroll
      for (int c = 0; c < 4; ++c) {
        int u0 = w * 256 + c * 64 + lane;
        *(f16x8*)(Ks + u0 * 8) = kreg[c];
        *(f16x8*)(Vs + u0 * 8) = vreg[c];
      }
    }
    __syncthreads();   // writes visible to all waves

    if (kt + 1 < kt1) ldregs(kt + 1);   // overlap next-tile loads with compute

    if (kt * 64 <= qbase + 31) {
      f32x16 sac[2];
#pragma unroll
      for (int mt = 0; mt < 2; ++mt)
#pragma unroll
        for (int r = 0; r < 16; ++r) sac[mt][r] = 0.f;
#pragma unroll
      for (int s8 = 0; s8 < 8; ++s8) {
#pragma unroll
        for (int mt = 0; mt < 2; ++mt) {
          f16x8 kf = *(const f16x8*)(Ks + ((s8 * 2 + hl) * 64 + mt * 32 + l5) * 8);
          sac[mt] = MFMA32(kf, qf[s8], sac[mt]);
        }
      }

      bool diag = (kt * 64 + 63 > qbase);
#pragma unroll
      for (int mt = 0; mt < 2; ++mt) {
#pragma unroll
        for (int g4 = 0; g4 < 4; ++g4) {
          f16x4 pk;
#pragma unroll
          for (int r = 0; r < 4; ++r) {
            int keyl = mt * 32 + g4 * 8 + hl * 4 + r;
            float p = __builtin_amdgcn_exp2f(fmaf(sac[mt][g4 * 4 + r], C1, -C2));
            if (diag && (kt * 64 + keyl > qrow)) p = 0.f;
            rs += p;
            pk[r] = (f16)p;
          }
          *(f16x4*)(&Ps[w][l5 * 72 + mt * 32 + g4 * 8 + hl * 4]) = pk;
        }
      }
      asm volatile("s_waitcnt lgkmcnt(0)" ::: "memory");  // same-wave P write->read

#pragma unroll
      for (int ks = 0; ks < 4; ++ks) {
        f16x8 pf = *(const f16x8*)(&Ps[w][l5 * 72 + ks * 16 + hl * 8]);
#pragma unroll
        for (int mt = 0; mt < 4; ++mt) {
          f16x8 vf = *(const f16x8*)(Vs + ((ks * 2 + hl) * 128 + mt * 32 + l5) * 8);
          oac[mt] = MFMA32(vf, pf, oac[mt]);
        }
      }
    }
  }

  float lsum = rs + __shfl_xor(rs, 32, 64);
  size_t ob = ((size_t)slot * 32 + bh) * S_LEN * DHEAD + (size_t)qrow * DHEAD;
#pragma unroll
  for (int mt = 0; mt < 4; ++mt) {
#pragma unroll
    for (int g4 = 0; g4 < 4; ++g4) {
      int d = mt * 32 + g4 * 8 + hl * 4;
      f16x4 ov = {(f16)oac[mt][g4 * 4 + 0], (f16)oac[mt][g4 * 4 + 1],
                  (f16)oac[mt][g4 * 4 + 2], (f16)oac[mt][g4 * 4 + 3]};
      *(f16x4*)(Opart + ob + d) = ov;
    }
  }
  if (hl == 0) Lpart[((size_t)slot * 32 + bh) * S_LEN + qrow] = lsum;
}

// ---------------- merge attn partials -> CTX blocked f16 ----------------
__global__ __launch_bounds__(256) void merge_kernel(const f16* __restrict__ Opart,
                                                    const float* __restrict__ Lpart,
                                                    f16* __restrict__ CTXb) {
  int t = blockIdx.x * 256 + threadIdx.x;  // 32*2048*16 threads
  int d8 = (t & 15) * 8;
  int q = (t >> 4) & 2047;
  int bh = t >> 15;
  int b = bh >> 4, hd = bh & 15;
  int ns = ((q >> 7) >= 8) ? 2 : 1;
  size_t o0 = ((size_t)bh * S_LEN + q) * DHEAD + d8;
  const size_t OSLOT = (size_t)32 * S_LEN * DHEAD;
  float l = Lpart[(size_t)bh * S_LEN + q];
  f16x8 a = *(const f16x8*)(Opart + o0);
  float acc[8];
#pragma unroll
  for (int j = 0; j < 8; ++j) acc[j] = (float)a[j];
  if (ns == 2) {
    l += Lpart[OSLOT / DHEAD + (size_t)bh * S_LEN + q];
    f16x8 a2 = *(const f16x8*)(Opart + OSLOT + o0);
#pragma unroll
    for (int j = 0; j < 8; ++j) acc[j] += (float)a2[j];
  }
  float inv = 1.0f / l;
  f16x8 o;
#pragma unroll
  for (int j = 0; j < 8; ++j) o[j] = (f16)(acc[j] * inv);
  // blocked write: row = b*S+q, col = hd*128+d8  (K = HDIM, KT = 64)
  int row = b * S_LEN + q;
  int col = hd * DHEAD + d8;
  int rt = row >> 7, rr = row & 127;
  int kt = col >> 5, kc = (col >> 3) & 3;
  *(f16x8*)(CTXb + ((size_t)rt * 64 + kt) * 4096 + (kc * 128 + rr) * 8) = o;
}

// ---------------- launch ----------------
extern "C" void kernel_launch(void* const* d_in, const int* in_sizes, int n_in,
                              void* d_out, int out_size, void* d_ws, size_t ws_size,
                              hipStream_t stream) {
  const float* X    = (const float*)d_in[0];
  const float* Wqkv = (const float*)d_in[2];
  const float* bqkv = (const float*)d_in[3];
  const float* Wout = (const float*)d_in[4];
  const float* bout = (const float*)d_in[5];
  float* out = (float*)d_out;

  char* ws = (char*)d_ws;
  f16* Xb    = (f16*)ws;  ws += (size_t)MROWS * HDIM * sizeof(f16);    // 16 MiB (reused as CTXb)
  f16* Wqkvb = (f16*)ws;  ws += (size_t)QKVN * HDIM * sizeof(f16);     // 24 MiB
  f16* Woutb = (f16*)ws;  ws += (size_t)HDIM * HDIM * sizeof(f16);     // 8 MiB
  f16* Qr    = (f16*)ws;  ws += (size_t)MROWS * HDIM * sizeof(f16);    // 16 MiB
  f16* KB    = (f16*)ws;  ws += (size_t)32 * 32 * 8192 * sizeof(f16);  // 16 MiB
  f16* VB    = (f16*)ws;  ws += (size_t)32 * 32 * 8192 * sizeof(f16);  // 16 MiB
  f16* Opart = (f16*)ws;  ws += (size_t)2 * 32 * S_LEN * DHEAD * sizeof(f16);  // 32 MiB
  float* Lpart = (float*)ws;  ws += (size_t)2 * 32 * S_LEN * sizeof(float);    // 512 KiB
  f16* CTXb  = Xb;        // Xb dead after QKV GEMM
  f16* Cpart = Opart;     // Opart dead after merge_kernel; 2*M*N*2B = 32 MiB fits

  prep_kernel<<<6144, 256, 0, stream>>>(X, Xb, Wqkv, Wqkvb, Wout, Woutb);

  // QKV GEMM: 256x384 tiles -> 16x16 = 256 blocks = exactly 1/CU, no tail
  gemm_qkv_kernel<<<dim3(QKVN / 384, MROWS / 256), 512, 0, stream>>>(
      Xb, Wqkvb, bqkv, Qr, KB, VB);

  attn_kernel<<<dim3(24, 32), 256, 0, stream>>>(Qr, KB, VB, Opart, Lpart);

  merge_kernel<<<(32 * S_LEN * 16) / 256, 256, 0, stream>>>(Opart, Lpart, CTXb);

  // out-proj: split-K 2 -> 8x16x2 = 256 blocks = exactly 1/CU, no tail
  gemm_out_kernel<<<dim3(HDIM / 256, MROWS / 256, 2), 512, 0, stream>>>(
      CTXb, Woutb, Cpart);

  merge_out_kernel<<<(MROWS * HDIM / 8) / 256, 256, 0, stream>>>(Cpart, bout, out);
}

// Round 7
// 368.156 us; speedup vs baseline: 1.4450x; 1.0302x over previous
//
#include <hip/hip_runtime.h>

#define S_LEN 2048
#define HDIM  2048
#define NHEADS 16
#define DHEAD 128
#define BATCH 2
#define MROWS (BATCH * S_LEN)   // 4096
#define QKVN  (3 * HDIM)        // 6144

typedef _Float16 f16;
typedef _Float16 f16x8 __attribute__((ext_vector_type(8)));
typedef _Float16 f16x4 __attribute__((ext_vector_type(4)));
typedef float    f32x4 __attribute__((ext_vector_type(4)));
typedef float    f32x16 __attribute__((ext_vector_type(16)));

typedef const __attribute__((address_space(1))) void* gas_ptr;
typedef __attribute__((address_space(3))) void*       las_ptr;

#define MFMA16(a, b, c)  __builtin_amdgcn_mfma_f32_16x16x32_f16(a, b, c, 0, 0, 0)
#define MFMA32(a, b, c)  __builtin_amdgcn_mfma_f32_32x32x16_f16(a, b, c, 0, 0, 0)

__device__ __forceinline__ void gl_lds16(const f16* g, f16* lds_wave_base) {
  __builtin_amdgcn_global_load_lds((gas_ptr)g, (las_ptr)lds_wave_base, 16, 0, 0);
}

// Blocked tile layout for GEMM operands: tile (rt, kt) of logical [rows][K] f16,
// 128 rows x 32 k, stored as [kc(4)][r(128)][8] (8 KB) at tile index rt*(K/32)+kt.

// ---------------- fused prep: X cvt + both weight transposes ------------------
__device__ __forceinline__ void transpose_tile(const float* __restrict__ W,
                                               f16* __restrict__ Wb,
                                               int K, int N, int k0, int n0,
                                               float* tile /*[64][65]*/) {
  int tr = threadIdx.x >> 4;
  int tc = (threadIdx.x & 15) * 4;
  int KT = K >> 5;
#pragma unroll
  for (int rr = 0; rr < 4; ++rr) {
    int r = rr * 16 + tr;
    float4 v = *(const float4*)(W + (size_t)(k0 + r) * N + n0 + tc);
    tile[r * 65 + tc + 0] = v.x; tile[r * 65 + tc + 1] = v.y;
    tile[r * 65 + tc + 2] = v.z; tile[r * 65 + tc + 3] = v.w;
  }
  __syncthreads();
#pragma unroll
  for (int rr = 0; rr < 4; ++rr) {
    int r = rr * 16 + tr;
    int n = n0 + r;
    int kBase = k0 + tc;
    f16x4 o;
#pragma unroll
    for (int c = 0; c < 4; ++c) o[c] = (f16)tile[(tc + c) * 65 + r];
    int nt = n >> 7, nn = n & 127;
    int kt = kBase >> 5, kc = (kBase >> 3) & 3, j = kBase & 7;
    *(f16x4*)(Wb + ((size_t)nt * KT + kt) * 4096 + (kc * 128 + nn) * 8 + j) = o;
  }
}

__global__ __launch_bounds__(256) void prep_kernel(const float* __restrict__ X,
                                                   f16* __restrict__ Xb,
                                                   const float* __restrict__ Wqkv,
                                                   f16* __restrict__ Wqkvb,
                                                   const float* __restrict__ Wout,
                                                   f16* __restrict__ Woutb) {
  __shared__ float tile[64 * 65];
  int bz = blockIdx.x;
  if (bz < 2048) {
    int kt = bz & 63, rt = bz >> 6;
    int t = threadIdx.x;
    int m = t >> 1, half = t & 1;
    const float* src = X + (size_t)(rt * 128 + m) * HDIM + kt * 32 + half * 16;
    float4 v0 = ((const float4*)src)[0];
    float4 v1 = ((const float4*)src)[1];
    float4 v2 = ((const float4*)src)[2];
    float4 v3 = ((const float4*)src)[3];
    f16x8 a = {(f16)v0.x, (f16)v0.y, (f16)v0.z, (f16)v0.w,
               (f16)v1.x, (f16)v1.y, (f16)v1.z, (f16)v1.w};
    f16x8 b = {(f16)v2.x, (f16)v2.y, (f16)v2.z, (f16)v2.w,
               (f16)v3.x, (f16)v3.y, (f16)v3.z, (f16)v3.w};
    f16* dst = Xb + ((size_t)rt * 64 + kt) * 4096 + ((half * 2) * 128 + m) * 8;
    *(f16x8*)dst = a;
    *(f16x8*)(dst + 1024) = b;
  } else if (bz < 5120) {
    int u = bz - 2048;                 // 96 n-blocks x 32 k-blocks
    int nx = u % 96, ky = u / 96;
    transpose_tile(Wqkv, Wqkvb, HDIM, QKVN, ky * 64, nx * 64, tile);
  } else {
    int u = bz - 5120;                 // 32 x 32
    int nx = u & 31, ky = u >> 5;
    transpose_tile(Wout, Woutb, HDIM, HDIM, ky * 64, nx * 64, tile);
  }
}

// ---------------- QKV GEMM: 256x384 tile, 8-wave, 3-buffer pipeline ----------
// EXACT R3 form (measured 114us): phase-locked cadence reads->barrier->
// lgkmcnt(0)->setprio 16-MFMA clusters; R4's rebalance/drain-removal regressed
// (137us) -- do not touch this schedule.
__global__ __launch_bounds__(512, 2) void gemm_qkv_kernel(const f16* __restrict__ Ablk,
                                                          const f16* __restrict__ Bblk,
                                                          const float* __restrict__ bias,
                                                          f16* __restrict__ Qr,
                                                          f16* __restrict__ KB,
                                                          f16* __restrict__ VB) {
  __shared__ f16 As[3][2][4096];   // [buf][row-half 128][blocked 128x32 tile]
  __shared__ f16 Bs[3][3][4096];   // [buf][col-third 128][blocked 128x32 tile]
  const int tid = threadIdx.x;
  const int lane = tid & 63, wv = tid >> 6;
  const int lhi = lane >> 4, llo = lane & 15;
  const int wr = wv >> 2, wc = wv & 3;       // 2M x 4N wave grid; wave owns 128x96

  // XCD-chunked swizzle: each XCD gets a 4bx x 8by cell (panel L2 locality)
  int lin = blockIdx.x + 16 * blockIdx.y;
  int xcd = lin & 7, slot = lin >> 3;        // slot in [0,32)
  int bx = (xcd & 3) * 4 + (slot & 3);
  int by = (xcd >> 2) * 8 + (slot >> 2);

  const int KT = HDIM >> 5;                  // 64 K-tiles
  const f16* Ab0 = Ablk + (size_t)(2 * by)     * KT * 4096;
  const f16* Ab1 = Ablk + (size_t)(2 * by + 1) * KT * 4096;
  const f16* Bb0 = Bblk + (size_t)(3 * bx)     * KT * 4096;
  const f16* Bb1 = Bblk + (size_t)(3 * bx + 1) * KT * 4096;
  const f16* Bb2 = Bblk + (size_t)(3 * bx + 2) * KT * 4096;

  f32x4 acc[8][6];
#pragma unroll
  for (int i = 0; i < 8; ++i)
#pragma unroll
    for (int j = 0; j < 6; ++j) acc[i][j] = (f32x4){0.f, 0.f, 0.f, 0.f};

  auto stA = [&](int bufi, int kt) {
    gl_lds16(Ab0 + (size_t)kt * 4096 + tid * 8, &As[bufi][0][0] + wv * 512);
    gl_lds16(Ab1 + (size_t)kt * 4096 + tid * 8, &As[bufi][1][0] + wv * 512);
  };
  auto stB = [&](int bufi, int kt) {
    gl_lds16(Bb0 + (size_t)kt * 4096 + tid * 8, &Bs[bufi][0][0] + wv * 512);
    gl_lds16(Bb1 + (size_t)kt * 4096 + tid * 8, &Bs[bufi][1][0] + wv * 512);
    gl_lds16(Bb2 + (size_t)kt * 4096 + tid * 8, &Bs[bufi][2][0] + wv * 512);
  };
  // B-fragment read: global col = wc*96 + j*16 (+llo); never straddles a third
  auto rdB = [&](int bufi, int j) -> f16x8 {
    int cg = wc * 96 + j * 16;
    return *(const f16x8*)(&Bs[bufi][cg >> 7][0] + (lhi * 128 + (cg & 127) + llo) * 8);
  };

  // prologue: tiles 0,1 in flight (10 loads/thread)
  stA(0, 0); stB(0, 0);
  stA(1, 1); stB(1, 1);

  for (int t = 0; t < KT; ++t) {
    const int buf = t % 3;
    const bool st = (t + 2 < KT);
    const int nb = (t + 2) % 3;

    if (t + 1 < KT) asm volatile("s_waitcnt vmcnt(5)" ::: "memory");
    else            asm volatile("s_waitcnt vmcnt(0)" ::: "memory");
    __builtin_amdgcn_s_barrier();   // tile t landed, collectively

    const f16* Ah = &As[buf][wr][0];
    f16x8 afr[8], bA, bB;

    // ---- pair 0: all 8 A-frags + B-frags 0,1; stage A(t+2) ----
#pragma unroll
    for (int i = 0; i < 8; ++i)
      afr[i] = *(const f16x8*)(Ah + (lhi * 128 + i * 16 + llo) * 8);
    bA = rdB(buf, 0); bB = rdB(buf, 1);
    if (st) stA(nb, t + 2);
    __builtin_amdgcn_s_barrier();
    asm volatile("s_waitcnt lgkmcnt(0)" ::: "memory");
    __builtin_amdgcn_s_setprio(1);
#pragma unroll
    for (int i = 0; i < 8; ++i) acc[i][0] = MFMA16(afr[i], bA, acc[i][0]);
#pragma unroll
    for (int i = 0; i < 8; ++i) acc[i][1] = MFMA16(afr[i], bB, acc[i][1]);
    __builtin_amdgcn_s_setprio(0);

    // ---- pair 1: B-frags 2,3; stage B(t+2) ----
    bA = rdB(buf, 2); bB = rdB(buf, 3);
    if (st) stB(nb, t + 2);
    __builtin_amdgcn_s_barrier();
    asm volatile("s_waitcnt lgkmcnt(0)" ::: "memory");
    __builtin_amdgcn_s_setprio(1);
#pragma unroll
    for (int i = 0; i < 8; ++i) acc[i][2] = MFMA16(afr[i], bA, acc[i][2]);
#pragma unroll
    for (int i = 0; i < 8; ++i) acc[i][3] = MFMA16(afr[i], bB, acc[i][3]);
    __builtin_amdgcn_s_setprio(0);

    // ---- pair 2: B-frags 4,5 ----
    bA = rdB(buf, 4); bB = rdB(buf, 5);
    __builtin_amdgcn_s_barrier();
    asm volatile("s_waitcnt lgkmcnt(0)" ::: "memory");
    __builtin_amdgcn_s_setprio(1);
#pragma unroll
    for (int i = 0; i < 8; ++i) acc[i][4] = MFMA16(afr[i], bA, acc[i][4]);
#pragma unroll
    for (int i = 0; i < 8; ++i) acc[i][5] = MFMA16(afr[i], bB, acc[i][5]);
    __builtin_amdgcn_s_setprio(0);
    // next tile-start barrier reconverges before buf reuse
  }

  // ---- epilogue: Q row-major / K,V attention-blocked scatter ----
#pragma unroll
  for (int j = 0; j < 6; ++j) {
    int col = bx * 384 + wc * 96 + j * 16 + llo;
    float bv = bias[col];
#pragma unroll
    for (int i = 0; i < 8; ++i) {
      int rowb = by * 256 + wr * 128 + i * 16 + lhi * 4;
      int region = col >> 11;  // 0:Q 1:K 2:V (per-element; 384-blocks straddle)
      if (region == 0) {
#pragma unroll
        for (int r = 0; r < 4; ++r)
          Qr[(size_t)(rowb + r) * HDIM + col] = (f16)(acc[i][j][r] + bv);
      } else if (region == 1) {
        int cK = col - HDIM;
        int hd = cK >> 7, d = cK & 127, g = d >> 3, dj = d & 7;
#pragma unroll
        for (int r = 0; r < 4; ++r) {
          int row = rowb + r;
          int b = row >> 11, s = row & 2047;
          int kt2 = s >> 6, key = s & 63;
          size_t addr = ((((size_t)(b * 16 + hd) * 32 + kt2) * 16 + g) * 64 + key) * 8 + dj;
          KB[addr] = (f16)(acc[i][j][r] + bv);
        }
      } else {
        int cV = col - 2 * HDIM;
        int hd = cV >> 7, d = cV & 127;
        int row = rowb;
        int b = row >> 11, s = row & 2047;
        int kt2 = s >> 6, key = s & 63;
        int kg = key >> 3, kj = key & 7;
        f16x4 pv = {(f16)(acc[i][j][0] + bv), (f16)(acc[i][j][1] + bv),
                    (f16)(acc[i][j][2] + bv), (f16)(acc[i][j][3] + bv)};
        size_t addr = ((((size_t)(b * 16 + hd) * 32 + kt2) * 8 + kg) * 128 + d) * 8 + kj;
        *(f16x4*)(VB + addr) = pv;
      }
    }
  }
}

// ---------------- out-proj GEMM: 256x256 tile, R3 phase-locked 4-buffer ------
// Grid 8x16x2 = 256 blocks = 1/CU, no tail.  Split-K by bz.  EXACT R3 form.
__global__ __launch_bounds__(512, 2) void gemm_out_kernel(const f16* __restrict__ Ablk,
                                                          const f16* __restrict__ Bblk,
                                                          f16* __restrict__ Cpart) {
  __shared__ f16 As[4][2][4096];
  __shared__ f16 Bs[4][2][4096];
  const int tid = threadIdx.x;
  const int lane = tid & 63, wv = tid >> 6;
  const int lhi = lane >> 4, llo = lane & 15;
  const int wr = wv >> 2, wc = wv & 3;

  // XCD-chunked swizzle
  int lin = blockIdx.x + 8 * (blockIdx.y + 16 * blockIdx.z);
  int xcd = lin & 7, slot = lin >> 3;        // slot in [0,32)
  int bx = slot & 7;
  int by = (xcd >> 1) * 4 + (slot >> 3);
  int bz = xcd & 1;

  const int KT = HDIM >> 5;                  // 64
  const int ntiles = KT >> 1;                // 32 per split
  const int t0 = bz * ntiles;

  const f16* Ab0 = Ablk + ((size_t)(2 * by)     * KT + t0) * 4096;
  const f16* Ab1 = Ablk + ((size_t)(2 * by + 1) * KT + t0) * 4096;
  const f16* Bb0 = Bblk + ((size_t)(2 * bx)     * KT + t0) * 4096;
  const f16* Bb1 = Bblk + ((size_t)(2 * bx + 1) * KT + t0) * 4096;

  f32x4 acc[8][4];
#pragma unroll
  for (int i = 0; i < 8; ++i)
#pragma unroll
    for (int j = 0; j < 4; ++j) acc[i][j] = (f32x4){0.f, 0.f, 0.f, 0.f};

  auto stA = [&](int bufi, int kt) {
    gl_lds16(Ab0 + (size_t)kt * 4096 + tid * 8, &As[bufi][0][0] + wv * 512);
    gl_lds16(Ab1 + (size_t)kt * 4096 + tid * 8, &As[bufi][1][0] + wv * 512);
  };
  auto stB = [&](int bufi, int kt) {
    gl_lds16(Bb0 + (size_t)kt * 4096 + tid * 8, &Bs[bufi][0][0] + wv * 512);
    gl_lds16(Bb1 + (size_t)kt * 4096 + tid * 8, &Bs[bufi][1][0] + wv * 512);
  };

#pragma unroll
  for (int u = 0; u < 3; ++u) { stA(u, u); stB(u, u); }

  for (int t = 0; t < ntiles; ++t) {
    const int buf = t & 3;
    const bool st = (t + 3 < ntiles);
    const int nb = (t + 3) & 3, ntile = t + 3;

    if (t + 2 < ntiles)      asm volatile("s_waitcnt vmcnt(8)" ::: "memory");
    else if (t + 1 < ntiles) asm volatile("s_waitcnt vmcnt(4)" ::: "memory");
    else                     asm volatile("s_waitcnt vmcnt(0)" ::: "memory");
    __builtin_amdgcn_s_barrier();

    const f16* Ah = &As[buf][wr][0];
    const f16* Bh = &Bs[buf][wc >> 1][0];
    f16x8 bfr[4], afr[4];

#pragma unroll
    for (int j = 0; j < 4; ++j)
      bfr[j] = *(const f16x8*)(Bh + (lhi * 128 + (wc & 1) * 64 + j * 16 + llo) * 8);
#pragma unroll
    for (int i = 0; i < 4; ++i)
      afr[i] = *(const f16x8*)(Ah + (lhi * 128 + i * 16 + llo) * 8);
    if (st) stA(nb, ntile);
    __builtin_amdgcn_s_barrier();
    asm volatile("s_waitcnt lgkmcnt(0)" ::: "memory");
    __builtin_amdgcn_s_setprio(1);
#pragma unroll
    for (int i = 0; i < 4; ++i)
#pragma unroll
      for (int j = 0; j < 4; ++j) acc[i][j] = MFMA16(afr[i], bfr[j], acc[i][j]);
    __builtin_amdgcn_s_setprio(0);
    __builtin_amdgcn_s_barrier();

#pragma unroll
    for (int i = 0; i < 4; ++i)
      afr[i] = *(const f16x8*)(Ah + (lhi * 128 + (i + 4) * 16 + llo) * 8);
    if (st) stB(nb, ntile);
    __builtin_amdgcn_s_barrier();
    asm volatile("s_waitcnt lgkmcnt(0)" ::: "memory");
    __builtin_amdgcn_s_setprio(1);
#pragma unroll
    for (int i = 0; i < 4; ++i)
#pragma unroll
      for (int j = 0; j < 4; ++j) acc[i + 4][j] = MFMA16(afr[i], bfr[j], acc[i + 4][j]);
    __builtin_amdgcn_s_setprio(0);
  }

#pragma unroll
  for (int j = 0; j < 4; ++j) {
    int col = bx * 256 + wc * 64 + j * 16 + llo;
#pragma unroll
    for (int i = 0; i < 8; ++i) {
      int rowb = by * 256 + wr * 128 + i * 16 + lhi * 4;
      size_t zoff = (size_t)bz * MROWS * HDIM;
#pragma unroll
      for (int r = 0; r < 4; ++r)
        Cpart[zoff + (size_t)(rowb + r) * HDIM + col] = (f16)acc[i][j][r];
    }
  }
}

// ---------------- bias + split-K merge -> f32 out ----------------
__global__ __launch_bounds__(256) void merge_out_kernel(const f16* __restrict__ Cpart,
                                                        const float* __restrict__ bias,
                                                        float* __restrict__ out) {
  int t = blockIdx.x * 256 + threadIdx.x;   // MROWS*HDIM/8 threads
  int col8 = (t & 255) * 8;
  int row = t >> 8;
  size_t base = (size_t)row * HDIM + col8;
  const size_t MN = (size_t)MROWS * HDIM;
  f16x8 a = *(const f16x8*)(Cpart + base);
  f16x8 b = *(const f16x8*)(Cpart + MN + base);
  float4 b0 = *(const float4*)(bias + col8);
  float4 b1 = *(const float4*)(bias + col8 + 4);
  float4 o0 = {(float)a[0] + (float)b[0] + b0.x, (float)a[1] + (float)b[1] + b0.y,
               (float)a[2] + (float)b[2] + b0.z, (float)a[3] + (float)b[3] + b0.w};
  float4 o1 = {(float)a[4] + (float)b[4] + b1.x, (float)a[5] + (float)b[5] + b1.y,
               (float)a[6] + (float)b[6] + b1.z, (float)a[7] + (float)b[7] + b1.w};
  *(float4*)(out + base) = o0;
  *(float4*)(out + base + 4) = o1;
}

// ---------------- causal flash attention: paired q-tiles, uniform blocks -----
// Block = q-tile pair (pr, 15-pr): waves 0-3 own the light tile, 4-7 the heavy
// tile, SHARING one staged K/V stream over the union k-range (32-2pr tiles).
// Per-SIMD MFMA work = 34 tile-units for EVERY block (uniform; old grid was
// 2..16) and K/V staging drops 272->200 units/bh.  Grid 8x32 = 256 blocks =
// 1/CU, no tail.  ONE barrier per k-tile: double-buffered Ks/Vs, gl_lds
// prefetch of t+1 issued right after tile-t's barrier (latency hides under
// tile-t compute; vmcnt(0) at tile top is then ~free).  Direct normalized
// output to blocked CTXb -- merge_kernel deleted.
// Race ledger: buf b^1 (write target for t+1) was last read at t-1; every
// wave passes the t-top barrier only after finishing t-1's compute.  Reads of
// buf b follow per-wave vmcnt(0) + barrier (collective).
__global__ __launch_bounds__(512, 1) void attn_kernel(const f16* __restrict__ Qr,
                                                      const f16* __restrict__ KB,
                                                      const f16* __restrict__ VB,
                                                      f16* __restrict__ CTXb) {
  __shared__ f16 Ks[2][1024 * 8];  // [buf][g(16)][key(64)][8]  16 KB each
  __shared__ f16 Vs[2][1024 * 8];  // [buf][kg(8)][d(128)][8]
  __shared__ f16 Ps[8][32 * 72];   // per-wave [q(32)][key(64)] stride 72

  int tid = threadIdx.x, lane = tid & 63, w = tid >> 6;
  int l5 = lane & 31, hl = lane >> 5;

  // XCD swizzle: 4 bh per XCD, all 8 pair-blocks of a bh on the same XCD
  int lin = blockIdx.x + 8 * blockIdx.y;     // 0..255
  int xcd = lin & 7, slot = lin >> 3;        // slot in [0,32)
  int bh = xcd + 8 * (slot & 3);
  int pr = slot >> 2;                        // pair index 0..7
  int qt = (w < 4) ? pr : (15 - pr);
  int b = bh >> 4, hd = bh & 15;
  int ktmax = 32 - 2 * pr;                   // union causal range of the pair

  int qbase = qt * 128 + (w & 3) * 32;
  int qrow = qbase + l5;

  const f16* qp = Qr + (size_t)(b * S_LEN + qrow) * HDIM + hd * DHEAD + hl * 8;
  f16x8 qf[8];
#pragma unroll
  for (int s8 = 0; s8 < 8; ++s8) qf[s8] = *(const f16x8*)(qp + s8 * 16);

  f32x16 oac[4];
#pragma unroll
  for (int mt = 0; mt < 4; ++mt)
#pragma unroll
    for (int r = 0; r < 16; ++r) oac[mt][r] = 0.f;
  float rs = 0.f;

  const float C1 = 0.12752747419986393f;   // log2(e)/sqrt(128)
  const float C2 = 11.541560327111708f;    // 8 * log2(e)

  const f16* KBb = KB + (size_t)bh * 32 * 8192;
  const f16* VBb = VB + (size_t)bh * 32 * 8192;

  // stage one k-tile: 8 waves x 2 chunks x (K,V) = 4 gl_lds per wave
  auto stage = [&](int bi, int kt) {
    const f16* Kt = KBb + (size_t)kt * 8192;
    const f16* Vt = VBb + (size_t)kt * 8192;
#pragma unroll
    for (int c = 0; c < 2; ++c) {
      int u0 = w * 128 + c * 64;
      gl_lds16(Kt + (size_t)(u0 + lane) * 8, Ks[bi] + u0 * 8);
      gl_lds16(Vt + (size_t)(u0 + lane) * 8, Vs[bi] + u0 * 8);
    }
  };

  stage(0, 0);   // prologue

  for (int kt = 0; kt < ktmax; ++kt) {
    int bi = kt & 1;
    asm volatile("s_waitcnt vmcnt(0)" ::: "memory");  // tile kt landed (per-wave)
    __builtin_amdgcn_s_barrier();                     // ... collectively
    if (kt + 1 < ktmax) stage(bi ^ 1, kt + 1);        // prefetch under compute

    if (kt * 64 <= qbase + 31) {
      f32x16 sac[2];
#pragma unroll
      for (int mt = 0; mt < 2; ++mt)
#pragma unroll
        for (int r = 0; r < 16; ++r) sac[mt][r] = 0.f;
#pragma unroll
      for (int s8 = 0; s8 < 8; ++s8) {
#pragma unroll
        for (int mt = 0; mt < 2; ++mt) {
          f16x8 kf = *(const f16x8*)(Ks[bi] + ((s8 * 2 + hl) * 64 + mt * 32 + l5) * 8);
          sac[mt] = MFMA32(kf, qf[s8], sac[mt]);
        }
      }

      bool diag = (kt * 64 + 63 > qbase);
#pragma unroll
      for (int mt = 0; mt < 2; ++mt) {
#pragma unroll
        for (int g4 = 0; g4 < 4; ++g4) {
          f16x4 pk;
#pragma unroll
          for (int r = 0; r < 4; ++r) {
            int keyl = mt * 32 + g4 * 8 + hl * 4 + r;
            float p = __builtin_amdgcn_exp2f(fmaf(sac[mt][g4 * 4 + r], C1, -C2));
            if (diag && (kt * 64 + keyl > qrow)) p = 0.f;
            rs += p;
            pk[r] = (f16)p;
          }
          *(f16x4*)(&Ps[w][l5 * 72 + mt * 32 + g4 * 8 + hl * 4]) = pk;
        }
      }
      asm volatile("s_waitcnt lgkmcnt(0)" ::: "memory");  // same-wave P write->read

#pragma unroll
      for (int ks = 0; ks < 4; ++ks) {
        f16x8 pf = *(const f16x8*)(&Ps[w][l5 * 72 + ks * 16 + hl * 8]);
#pragma unroll
        for (int mt = 0; mt < 4; ++mt) {
          f16x8 vf = *(const f16x8*)(Vs[bi] + ((ks * 2 + hl) * 128 + mt * 32 + l5) * 8);
          oac[mt] = MFMA32(vf, pf, oac[mt]);
        }
      }
    }
  }

  // direct normalized output -> blocked CTXb (row = b*S+qrow, col = hd*128+d)
  float lsum = rs + __shfl_xor(rs, 32, 64);
  float inv = 1.0f / lsum;
  int row = b * S_LEN + qrow;
  int rt = row >> 7, rr = row & 127;
#pragma unroll
  for (int mt = 0; mt < 4; ++mt) {
#pragma unroll
    for (int g4 = 0; g4 < 4; ++g4) {
      int d = mt * 32 + g4 * 8 + hl * 4;
      int col = hd * DHEAD + d;
      f16x4 ov = {(f16)(oac[mt][g4 * 4 + 0] * inv), (f16)(oac[mt][g4 * 4 + 1] * inv),
                  (f16)(oac[mt][g4 * 4 + 2] * inv), (f16)(oac[mt][g4 * 4 + 3] * inv)};
      *(f16x4*)(CTXb + ((size_t)rt * 64 + (col >> 5)) * 4096 +
                (((col >> 3) & 3) * 128 + rr) * 8 + (col & 7)) = ov;
    }
  }
}

// ---------------- launch ----------------
extern "C" void kernel_launch(void* const* d_in, const int* in_sizes, int n_in,
                              void* d_out, int out_size, void* d_ws, size_t ws_size,
                              hipStream_t stream) {
  const float* X    = (const float*)d_in[0];
  const float* Wqkv = (const float*)d_in[2];
  const float* bqkv = (const float*)d_in[3];
  const float* Wout = (const float*)d_in[4];
  const float* bout = (const float*)d_in[5];
  float* out = (float*)d_out;

  char* ws = (char*)d_ws;
  f16* Xb    = (f16*)ws;  ws += (size_t)MROWS * HDIM * sizeof(f16);    // 16 MiB (reused as CTXb)
  f16* Wqkvb = (f16*)ws;  ws += (size_t)QKVN * HDIM * sizeof(f16);     // 24 MiB
  f16* Woutb = (f16*)ws;  ws += (size_t)HDIM * HDIM * sizeof(f16);     // 8 MiB
  f16* Qr    = (f16*)ws;  ws += (size_t)MROWS * HDIM * sizeof(f16);    // 16 MiB
  f16* KB    = (f16*)ws;  ws += (size_t)32 * 32 * 8192 * sizeof(f16);  // 16 MiB
  f16* VB    = (f16*)ws;  ws += (size_t)32 * 32 * 8192 * sizeof(f16);  // 16 MiB
  f16* Cpart = (f16*)ws;  ws += (size_t)2 * MROWS * HDIM * sizeof(f16);  // 32 MiB
  f16* CTXb  = Xb;        // Xb dead after QKV GEMM

  prep_kernel<<<6144, 256, 0, stream>>>(X, Xb, Wqkv, Wqkvb, Wout, Woutb);

  // QKV GEMM: 256x384 tiles -> 16x16 = 256 blocks = exactly 1/CU, no tail
  gemm_qkv_kernel<<<dim3(QKVN / 384, MROWS / 256), 512, 0, stream>>>(
      Xb, Wqkvb, bqkv, Qr, KB, VB);

  // attn: 8 pair-blocks x 32 bh = 256 blocks, direct normalized CTXb output
  attn_kernel<<<dim3(8, 32), 512, 0, stream>>>(Qr, KB, VB, CTXb);

  // out-proj: split-K 2 -> 8x16x2 = 256 blocks = exactly 1/CU, no tail
  gemm_out_kernel<<<dim3(HDIM / 256, MROWS / 256, 2), 512, 0, stream>>>(
      CTXb, Woutb, Cpart);

  merge_out_kernel<<<(MROWS * HDIM / 8) / 256, 256, 0, stream>>>(Cpart, bout, out);
}